// Round 6
// baseline (640.894 us; speedup 1.0000x reference)
//
#include <hip/hip_runtime.h>
#include <hip/hip_bf16.h>

// ---------------------------------------------------------------------------
// GCN surface: 4x GCNConv(tanh) + global max/mean pool + 3-layer MLP
// Round 19 (visibility + GEMM epilogue):
//   - budget hole: 7x52us msgpass + ~110us modeled hidden != 609us total;
//     ~125us unaccounted. Force diagnosis: re-merge layers-1..3 msgpass to
//     full W=256 (half-split twice-proven neutral; -3 dispatches) so next
//     top-5 exposes the largest hidden kernel with counters.
//   - GEMM epilogue vectorized: activation -> LDS bf16 tile (stride 132,
//     conflict-free writes) -> uint4 coalesced C stores (8 instrs vs 64
//     scalar 2B stores). Attacks the suspected hidden store cost.
//   - keep: atomic-free CSR build + pooling, parallel MLP, ushort col,
//     BK=64 GEMM, prep fusion, 8-deep msgpass inner loop.
// ---------------------------------------------------------------------------

#define NNODES 50000
#define DDIM 256
#define NBUCK 196            // ceil(50000/256) buckets of 256 nodes
#define BCAP 16384           // slots per bucket region (mean 8163, max ~8500)
#define CHUNK_AB 6400        // edges per build_partition block
#define NGRAPH 64
#define PCHUNK 8             // pool chunks per graph

typedef __attribute__((ext_vector_type(8))) short short8;
typedef __attribute__((ext_vector_type(4))) float float4_;
typedef __attribute__((ext_vector_type(2))) float float2_;

__device__ __forceinline__ float fast_tanh(float x) {
    float e = __expf(2.0f * x);
    return 1.0f - 2.0f / (e + 1.0f);
}

__device__ __forceinline__ float bf2f(unsigned short u) {
    return __uint_as_float(((unsigned)u) << 16);
}
__device__ __forceinline__ unsigned short f2bf(float f) {
    unsigned u = __float_as_uint(f);
    u = u + 0x7fffu + ((u >> 16) & 1u);   // round-to-nearest-even
    return (unsigned short)(u >> 16);
}

// ---------------- CSR build: bucketed counting sort (no fabric atomics) -----
__global__ void build_partition(const int* __restrict__ ei, int* __restrict__ bcnt,
                                unsigned* __restrict__ pairs, int E) {
    __shared__ int hist[NBUCK];
    __shared__ int base[NBUCK];
    __shared__ int cursor[NBUCK];
    int t = threadIdx.x;
    int e0 = blockIdx.x * CHUNK_AB;
    int lim = E - e0;
    if (lim > CHUNK_AB) lim = CHUNK_AB;
    if (t < NBUCK) { hist[t] = 0; cursor[t] = 0; }
    __syncthreads();
    for (int i = t; i < lim; i += 256)
        atomicAdd(&hist[ei[E + e0 + i] >> 8], 1);
    __syncthreads();
    if (t < NBUCK) {
        int h = hist[t];
        base[t] = h ? atomicAdd(&bcnt[t], h) : 0;
    }
    __syncthreads();
    for (int i = t; i < lim; i += 256) {
        int dst = ei[E + e0 + i];
        int src = ei[e0 + i];
        int b = dst >> 8;
        int r = atomicAdd(&cursor[b], 1);
        pairs[(size_t)b * BCAP + base[b] + r] =
            ((unsigned)(dst & 255) << 16) | (unsigned)src;
    }
}

__global__ void build_csr(const unsigned* __restrict__ pairs, const int* __restrict__ bcnt,
                          int* __restrict__ deg, int* __restrict__ rowptr,
                          float* __restrict__ dis, unsigned short* __restrict__ col, int N) {
    __shared__ int sc[256];
    __shared__ int hist[256];
    __shared__ int cursor[256];
    int b = blockIdx.x;
    int t = threadIdx.x;
    sc[t] = (t < NBUCK) ? bcnt[t] : 0;
    __syncthreads();
    for (int off = 1; off < 256; off <<= 1) {
        int v = (t >= off) ? sc[t - off] : 0;
        __syncthreads();
        sc[t] += v;
        __syncthreads();
    }
    int bstart = (b == 0) ? 0 : sc[b - 1];
    int cnt = bcnt[b];
    __syncthreads();          // everyone has bstart before sc is reused
    hist[t] = 0; cursor[t] = 0;
    __syncthreads();
    const unsigned* bp = pairs + (size_t)b * BCAP;
    for (int i = t; i < cnt; i += 256)
        atomicAdd(&hist[bp[i] >> 16], 1);
    __syncthreads();
    sc[t] = hist[t];
    __syncthreads();
    for (int off = 1; off < 256; off <<= 1) {
        int v = (t >= off) ? sc[t - off] : 0;
        __syncthreads();
        sc[t] += v;
        __syncthreads();
    }
    int n = b * 256 + t;
    if (n < N) {
        int d = hist[t];
        deg[n] = d;
        dis[n] = rsqrtf(1.0f + (float)d);
        rowptr[n] = bstart + sc[t] - d;   // exclusive
    }
    __syncthreads();
    for (int i = t; i < cnt; i += 256) {
        unsigned p = bp[i];
        int low = p >> 16;
        int r = atomicAdd(&cursor[low], 1);
        col[bstart + (sc[low] - hist[low]) + r] = (unsigned short)(p & 0xffffu);
    }
}

// ---------------- prep: cast x (pre-scaled by dis) + 4 weight transposes ----
#define CAST_BLOCKS ((NNODES * 128) / 256)     // 25000
__global__ void prep_kernel(const float* __restrict__ x, const float* __restrict__ dis,
                            unsigned short* __restrict__ xh,
                            const float* __restrict__ W0, const float* __restrict__ W1,
                            const float* __restrict__ W2, const float* __restrict__ W3,
                            unsigned short* __restrict__ wt0, unsigned short* __restrict__ wt1,
                            unsigned short* __restrict__ wt2, unsigned short* __restrict__ wt3) {
    int b = blockIdx.x;
    int t = threadIdx.x;
    if (b < CAST_BLOCKS) {
        int i = b * 256 + t;
        xh[i] = f2bf(x[i] * dis[i >> 7]);   // 128 feats per row
        return;
    }
    b -= CAST_BLOCKS;
    const float* W; unsigned short* Wt; int K; int k;
    if (b < 128)      { W = W0; Wt = wt0; K = 128; k = b; }
    else if (b < 384) { W = W1; Wt = wt1; K = 256; k = b - 128; }
    else if (b < 640) { W = W2; Wt = wt2; K = 256; k = b - 384; }
    else              { W = W3; Wt = wt3; K = 256; k = b - 640; }
    Wt[t * K + k] = f2bf(W[k * 256 + t]);
}

// ---------------- message passing (W = width, S = row stride) ----------------
__device__ __forceinline__ void paddu(float2_* acc, uint4 u) {
    float2_ v0 = {__uint_as_float(u.x << 16), __uint_as_float(u.x & 0xffff0000u)};
    float2_ v1 = {__uint_as_float(u.y << 16), __uint_as_float(u.y & 0xffff0000u)};
    float2_ v2 = {__uint_as_float(u.z << 16), __uint_as_float(u.z & 0xffff0000u)};
    float2_ v3 = {__uint_as_float(u.w << 16), __uint_as_float(u.w & 0xffff0000u)};
    acc[0] += v0; acc[1] += v1; acc[2] += v2; acc[3] += v3;
}
__device__ __forceinline__ void paddw(float2_* acc, uint4 u, float w) {
    float2_ w2 = {w, w};
    float2_ v0 = {__uint_as_float(u.x << 16), __uint_as_float(u.x & 0xffff0000u)};
    float2_ v1 = {__uint_as_float(u.y << 16), __uint_as_float(u.y & 0xffff0000u)};
    float2_ v2 = {__uint_as_float(u.z << 16), __uint_as_float(u.z & 0xffff0000u)};
    float2_ v3 = {__uint_as_float(u.w << 16), __uint_as_float(u.w & 0xffff0000u)};
    acc[0] += v0 * w2; acc[1] += v1 * w2; acc[2] += v2 * w2; acc[3] += v3 * w2;
}

template <int W, int S, bool FINALIZE>
__global__ void msgpass_bf16(const unsigned short* __restrict__ in,
                             unsigned short* __restrict__ out,
                             const int* __restrict__ rowptr, const int* __restrict__ deg,
                             const unsigned short* __restrict__ col,
                             const float* __restrict__ dis, const float* __restrict__ bias) {
    constexpr int L = W / 8;      // lanes per edge (16 for W=128, 32 for W=256)
    constexpr int P = 64 / L;     // edges per wave-issue (4 / 2)
    int lane = threadIdx.x & 63;
    int wav  = threadIdx.x >> 6;
    int n = blockIdx.x * 4 + wav;   // block = 256 threads = 4 waves
    if (n >= NNODES) return;
    int part = lane / L;
    int sl   = lane % L;
    int start = rowptr[n];
    int cnt   = deg[n];
    float dn = dis[n];
    const uint4* inb = (const uint4*)in + sl;   // lane-fixed base
    float2_ acc[4];
#pragma unroll
    for (int j = 0; j < 4; ++j) { float2_ z = {0.0f, 0.0f}; acc[j] = z; }

    int e = 0;
    // 8-deep: 8 cols then 8 row-loads in flight, then unpack (static indices)
    for (; e + 8 * P <= cnt; e += 8 * P) {
        int c[8];
        uint4 u[8];
#pragma unroll
        for (int q = 0; q < 8; ++q)
            c[q] = col[start + e + q * P + part];
#pragma unroll
        for (int q = 0; q < 8; ++q)
            u[q] = *(inb + (size_t)c[q] * (S / 8));
#pragma unroll
        for (int q = 0; q < 8; ++q)
            paddu(acc, u[q]);
    }
    for (; e + 4 * P <= cnt; e += 4 * P) {
        int c0 = col[start + e + part];
        int c1 = col[start + e + P + part];
        int c2 = col[start + e + 2 * P + part];
        int c3 = col[start + e + 3 * P + part];
        uint4 u0 = *(inb + (size_t)c0 * (S / 8));
        uint4 u1 = *(inb + (size_t)c1 * (S / 8));
        uint4 u2 = *(inb + (size_t)c2 * (S / 8));
        uint4 u3 = *(inb + (size_t)c3 * (S / 8));
        paddu(acc, u0);
        paddu(acc, u1);
        paddu(acc, u2);
        paddu(acc, u3);
    }
    for (; e + P <= cnt; e += P) {
        int c = col[start + e + part];
        uint4 u = *(inb + (size_t)c * (S / 8));
        paddu(acc, u);
    }
    int r = cnt - e;
    if (r > 0) {
        int c = (part < r) ? (int)col[start + e + part] : n;
        float w = (part < r) ? 1.0f : 0.0f;
        uint4 u = *(inb + (size_t)c * (S / 8));
        paddw(acc, u, w);
    }
    {   // self term: + in[n] (part 0 only)
        float w = (part == 0) ? 1.0f : 0.0f;
        uint4 u = *(inb + (size_t)n * (S / 8));
        paddw(acc, u, w);
    }
    // reduce across parts (butterfly)
#pragma unroll
    for (int j = 0; j < 4; ++j) {
#pragma unroll
        for (int h = 0; h < 2; ++h) {
            if (P == 4) acc[j][h] += __shfl(acc[j][h], lane ^ 16);
            acc[j][h] += __shfl(acc[j][h], lane ^ 32);
        }
    }
    if (part == 0) {
        float a[8] = {acc[0][0], acc[0][1], acc[1][0], acc[1][1],
                      acc[2][0], acc[2][1], acc[3][0], acc[3][1]};
        if (FINALIZE) {
#pragma unroll
            for (int j = 0; j < 8; ++j)
                a[j] = fast_tanh(fmaf(a[j], dn, bias[sl * 8 + j]));
        } else {
#pragma unroll
            for (int j = 0; j < 8; ++j)
                a[j] *= dn;
        }
        uint4 o;
        o.x = (unsigned)f2bf(a[0]) | ((unsigned)f2bf(a[1]) << 16);
        o.y = (unsigned)f2bf(a[2]) | ((unsigned)f2bf(a[3]) << 16);
        o.z = (unsigned)f2bf(a[4]) | ((unsigned)f2bf(a[5]) << 16);
        o.w = (unsigned)f2bf(a[6]) | ((unsigned)f2bf(a[7]) << 16);
        *((uint4*)(out + (size_t)n * S) + sl) = o;
    }
}

// ---------------- MFMA GEMM: C[N,256] = A[N,K] * W[K,256], BK=64 ----------
// Epilogue: activation in regs -> bf16 tile in LDS (stride 132, conflict-free
// writes) -> coalesced uint4 stores.
template <int K, bool TANH>
__launch_bounds__(256, 2)
__global__ void gemm_mfma(const short* __restrict__ A, const short* __restrict__ Bt,
                          const float* __restrict__ bias, const float* __restrict__ dis,
                          unsigned short* __restrict__ C, int N) {
    constexpr int PK = 72;   // 64 + 8 pad (16B-aligned segments)
    constexpr int TS = 132;  // epilogue tile stride (shorts)
    __shared__ __align__(16) short smem[2 * 128 * PK];   // 36,864 B
    short* As = smem;
    short* Bs = smem + 128 * PK;
    int t = threadIdx.x;
    int lane = t & 63;
    int w    = t >> 6;
    int wr = w & 1;
    int wc = w >> 1;
    int m0 = blockIdx.x * 128;
    int n0 = blockIdx.y * 128;

    int srow = t >> 2;           // 0..63
    int koff = (t & 3) * 8;      // 0,8,16,24
    int arow0 = m0 + srow;      if (arow0 > N - 1) arow0 = N - 1;
    int arow1 = m0 + 64 + srow; if (arow1 > N - 1) arow1 = N - 1;
    const short8* ap0 = (const short8*)(A + (size_t)arow0 * K + koff);
    const short8* ap1 = (const short8*)(A + (size_t)arow1 * K + koff);
    const short8* bp0 = (const short8*)(Bt + (size_t)(n0 + srow) * K + koff);
    const short8* bp1 = (const short8*)(Bt + (size_t)(n0 + 64 + srow) * K + koff);

    float4_ acc[4][4];
#pragma unroll
    for (int i = 0; i < 4; ++i)
#pragma unroll
        for (int j = 0; j < 4; ++j) {
            float4_ z = {0.0f, 0.0f, 0.0f, 0.0f};
            acc[i][j] = z;
        }

    constexpr int NKB = K / 64;       // 4 for K=256, 2 for K=128
    int g = lane >> 4;
    int r = lane & 15;

    short8 a00 = ap0[0], a01 = ap0[4];
    short8 a10 = ap1[0], a11 = ap1[4];
    short8 b00 = bp0[0], b01 = bp0[4];
    short8 b10 = bp1[0], b11 = bp1[4];

    for (int kb = 0; kb < NKB; ++kb) {
        __syncthreads();
        *(short8*)&As[srow * PK + koff]             = a00;
        *(short8*)&As[srow * PK + koff + 32]        = a01;
        *(short8*)&As[(64 + srow) * PK + koff]      = a10;
        *(short8*)&As[(64 + srow) * PK + koff + 32] = a11;
        *(short8*)&Bs[srow * PK + koff]             = b00;
        *(short8*)&Bs[srow * PK + koff + 32]        = b01;
        *(short8*)&Bs[(64 + srow) * PK + koff]      = b10;
        *(short8*)&Bs[(64 + srow) * PK + koff + 32] = b11;
        __syncthreads();
        if (kb + 1 < NKB) {
            int o = (kb + 1) * 8;
            a00 = ap0[o]; a01 = ap0[o + 4];
            a10 = ap1[o]; a11 = ap1[o + 4];
            b00 = bp0[o]; b01 = bp0[o + 4];
            b10 = bp1[o]; b11 = bp1[o + 4];
        }
#pragma unroll
        for (int s = 0; s < 2; ++s) {
            short8 af[4], bfr[4];
#pragma unroll
            for (int i = 0; i < 4; ++i)
                af[i] = *(const short8*)&As[(wr * 64 + i * 16 + r) * PK + s * 32 + g * 8];
#pragma unroll
            for (int j = 0; j < 4; ++j)
                bfr[j] = *(const short8*)&Bs[(wc * 64 + j * 16 + r) * PK + s * 32 + g * 8];
#pragma unroll
            for (int i = 0; i < 4; ++i)
#pragma unroll
                for (int j = 0; j < 4; ++j)
                    acc[i][j] = __builtin_amdgcn_mfma_f32_16x16x32_bf16(af[i], bfr[j],
                                                                        acc[i][j], 0, 0, 0);
        }
    }

    // ---- epilogue: activation -> LDS bf16 tile -> coalesced uint4 stores ----
    __syncthreads();           // all frag reads done; smem reused as T[128][TS]
    short* T = smem;
#pragma unroll
    for (int i = 0; i < 4; ++i) {
        int lr0 = wr * 64 + i * 16 + g * 4;
        int grow = m0 + lr0;
        float d0 = TANH ? 0.0f : dis[(grow + 0 < N) ? grow + 0 : N - 1];
        float d1 = TANH ? 0.0f : dis[(grow + 1 < N) ? grow + 1 : N - 1];
        float d2 = TANH ? 0.0f : dis[(grow + 2 < N) ? grow + 2 : N - 1];
        float d3 = TANH ? 0.0f : dis[(grow + 3 < N) ? grow + 3 : N - 1];
        float dd[4] = {d0, d1, d2, d3};
#pragma unroll
        for (int j = 0; j < 4; ++j) {
            int lcol = wc * 64 + j * 16 + r;
            float bb = TANH ? bias[n0 + lcol] : 0.0f;
#pragma unroll
            for (int rr = 0; rr < 4; ++rr) {
                float v = acc[i][j][rr];
                if (TANH) v = fast_tanh(v + bb);
                else      v = v * dd[rr];
                T[(lr0 + rr) * TS + lcol] = (short)f2bf(v);
            }
        }
    }
    __syncthreads();
    {
        int row = t >> 1;          // 0..127
        int h   = t & 1;           // 0..1
        int grow = m0 + row;
        if (grow < N) {
            const short* src = &T[row * TS + h * 64];
            uint4* dstp = (uint4*)(C + (size_t)grow * 256 + n0 + h * 64);
#pragma unroll
            for (int k = 0; k < 8; ++k)
                dstp[k] = *(const uint4*)(src + k * 8);
        }
    }
}

// ---------------- pooling: sorted batch, per-graph chunks, NO atomics -------
__global__ void pool_kernel(const unsigned short* __restrict__ act,
                            const int* __restrict__ batch,
                            float* __restrict__ psum, float* __restrict__ pmax,
                            int* __restrict__ gcnt, int N) {
    int g = blockIdx.x >> 3;        // graph
    int c = blockIdx.x & 7;         // chunk
    int t = threadIdx.x;            // 256 = DDIM
    __shared__ int bounds[2];
    if (t < 2) {
        int target = g + t;         // t=0: first idx with batch>=g; t=1: >=g+1
        int lo = 0, hi = N;
        while (lo < hi) {
            int m = (lo + hi) >> 1;
            if (batch[m] < target) lo = m + 1; else hi = m;
        }
        bounds[t] = lo;
    }
    __syncthreads();
    int s = bounds[0];
    int e = bounds[1];
    int len = e - s;
    if (len < 0) len = 0;
    if (c == 0 && t == 0) gcnt[g] = len;
    int n0 = s + (int)(((long long)len * c) >> 3);
    int n1 = s + (int)(((long long)len * (c + 1)) >> 3);
    float sum = 0.0f, mx = -2.0f;
    int n = n0;
    for (; n + 4 <= n1; n += 4) {
        float v0 = bf2f(act[(size_t)(n + 0) * DDIM + t]);
        float v1 = bf2f(act[(size_t)(n + 1) * DDIM + t]);
        float v2 = bf2f(act[(size_t)(n + 2) * DDIM + t]);
        float v3 = bf2f(act[(size_t)(n + 3) * DDIM + t]);
        sum += (v0 + v1) + (v2 + v3);
        mx = fmaxf(fmaxf(mx, v0), fmaxf(fmaxf(v1, v2), v3));
    }
    for (; n < n1; ++n) {
        float v = bf2f(act[(size_t)n * DDIM + t]);
        sum += v;
        mx = fmaxf(mx, v);
    }
    psum[(size_t)blockIdx.x * DDIM + t] = sum;
    pmax[(size_t)blockIdx.x * DDIM + t] = mx;
}

// ---------------- fused MLP, 1024 thr/block, k-split + LDS combine ----------
__launch_bounds__(1024, 1)
__global__ void mlp_kernel(const float* __restrict__ psum, const float* __restrict__ pmax,
                           const int* __restrict__ gcnt,
                           const float* __restrict__ fc1_w, const float* __restrict__ fc1_b,
                           const float* __restrict__ fc2_w, const float* __restrict__ fc2_b,
                           const float* __restrict__ out_w, const float* __restrict__ out_b,
                           float* __restrict__ out) {
    int g = blockIdx.x;
    int t = threadIdx.x;   // 1024
    __shared__ float gv[512];
    __shared__ float t1[512];
    __shared__ float t2[256];
    __shared__ float ps[2][512];
    __shared__ float ps2[4][256];
    __shared__ float pso[32][16];
    if (t < 512) {
        if (t < 256) {
            float m = pmax[(size_t)(g * PCHUNK) * DDIM + t];
#pragma unroll
            for (int c = 1; c < PCHUNK; ++c)
                m = fmaxf(m, pmax[(size_t)(g * PCHUNK + c) * DDIM + t]);
            gv[t] = m;
        } else {
            int tt = t - 256;
            float sm = 0.0f;
#pragma unroll
            for (int c = 0; c < PCHUNK; ++c)
                sm += psum[(size_t)(g * PCHUNK + c) * DDIM + tt];
            float cnt = fmaxf((float)gcnt[g], 1.0f);
            gv[t] = sm / cnt;
        }
    }
    __syncthreads();
    {   // fc1: j in [0,512), h in {0,1}, 256-long partial each
        int j = t & 511;
        int h = t >> 9;
        float a = 0.0f;
        const float* wp = fc1_w + (size_t)(h * 256) * 512 + j;
#pragma unroll 8
        for (int k = 0; k < 256; ++k)
            a = fmaf(gv[h * 256 + k], wp[(size_t)k * 512], a);
        ps[h][j] = a;
    }
    __syncthreads();
    if (t < 512)
        t1[t] = fmaxf(ps[0][t] + ps[1][t] + fc1_b[t], 0.0f);
    __syncthreads();
    {   // fc2: j in [0,256), h in {0..3}, 128-long partial each
        int j = t & 255;
        int h = t >> 8;
        float a = 0.0f;
        const float* wp = fc2_w + (size_t)(h * 128) * 256 + j;
#pragma unroll 8
        for (int k = 0; k < 128; ++k)
            a = fmaf(t1[h * 128 + k], wp[(size_t)k * 256], a);
        ps2[h][j] = a;
    }
    __syncthreads();
    if (t < 256)
        t2[t] = fmaxf(ps2[0][t] + ps2[1][t] + ps2[2][t] + ps2[3][t] + fc2_b[t], 0.0f);
    __syncthreads();
    if (t < 512) {   // out: j in [0,16) (j<10 live), h in [0,32), 8-long partial
        int j = t & 15;
        int h = t >> 4;
        float a = 0.0f;
        if (j < 10) {
#pragma unroll
            for (int k = 0; k < 8; ++k)
                a = fmaf(t2[h * 8 + k], out_w[(size_t)(h * 8 + k) * 10 + j], a);
        }
        pso[h][j] = a;
    }
    __syncthreads();
    if (t < 10) {
        float o = out_b[t];
#pragma unroll
        for (int h = 0; h < 32; ++h)
            o += pso[h][t];
        out[g * 10 + t] = o;
    }
}

// ---------------------------------------------------------------------------
extern "C" void kernel_launch(void* const* d_in, const int* in_sizes, int n_in,
                              void* d_out, int out_size, void* d_ws, size_t ws_size,
                              hipStream_t stream) {
    const float* x      = (const float*)d_in[0];
    const int*   ei     = (const int*)d_in[1];
    const int*   batch  = (const int*)d_in[2];
    const float* W0     = (const float*)d_in[3];
    const float* b0     = (const float*)d_in[4];
    const float* W1     = (const float*)d_in[5];
    const float* b1     = (const float*)d_in[6];
    const float* W2     = (const float*)d_in[7];
    const float* b2     = (const float*)d_in[8];
    const float* W3     = (const float*)d_in[9];
    const float* b3     = (const float*)d_in[10];
    const float* fc1_w  = (const float*)d_in[11];
    const float* fc1_b  = (const float*)d_in[12];
    const float* fc2_w  = (const float*)d_in[13];
    const float* fc2_b  = (const float*)d_in[14];
    const float* out_w  = (const float*)d_in[15];
    const float* out_b  = (const float*)d_in[16];
    float* out = (float*)d_out;

    const int N = in_sizes[2];          // 50000
    const int E = in_sizes[1] / 2;      // 1600000

    // workspace layout (bytes)
    char* ws = (char*)d_ws;
    const size_t off_deg    = 0;          // 200000 (written by build_csr)
    const size_t off_gcnt   = 331264;     // 256 (written by pool, no zero)
    const size_t off_dis    = 331776;     // 200000
    const size_t off_rowptr = 531968;     // 200000
    const size_t off_bcnt   = 732160;     // 1024   (zeroed)
    const size_t off_col    = 932352;     // E*2 = 3200000 (ushort)
    const size_t off_xh     = 7332352;    // 12800000
    const size_t off_wt0    = 20132352;   // 65536
    const size_t off_wt1    = 20197888;   // 131072
    const size_t off_wt2    = 20328960;   // 131072
    const size_t off_wt3    = 20460032;   // 131072
    const size_t off_bufA   = 20591104;   // 25600000
    const size_t off_bufB   = 46191104;   // 25600000

    int*            deg    = (int*)(ws + off_deg);
    int*            gcnt   = (int*)(ws + off_gcnt);
    float*          dis    = (float*)(ws + off_dis);
    int*            rowptr = (int*)(ws + off_rowptr);
    int*            bcnt   = (int*)(ws + off_bcnt);
    unsigned short* col    = (unsigned short*)(ws + off_col);
    unsigned short* xh     = (unsigned short*)(ws + off_xh);
    short*          wt0    = (short*)(ws + off_wt0);
    short*          wt1    = (short*)(ws + off_wt1);
    short*          wt2    = (short*)(ws + off_wt2);
    short*          wt3    = (short*)(ws + off_wt3);
    unsigned short* bufA   = (unsigned short*)(ws + off_bufA);
    unsigned short* bufB   = (unsigned short*)(ws + off_bufB);
    // pairs overlay: 196*16384*4 = 12.84 MB, dead before first GEMM writes bufA
    unsigned*       pairs  = (unsigned*)(ws + off_bufA);
    // pool partials overlay on xh (dead after layer-0 msgpass)
    float*          psum   = (float*)(ws + off_xh);
    float*          pmax   = (float*)(ws + off_xh + 524288);

    hipMemsetAsync(ws + off_bcnt, 0, 1024, stream);

    // CSR build (atomic-free hot path)
    build_partition<<<(E + CHUNK_AB - 1) / CHUNK_AB, 256, 0, stream>>>(ei, bcnt, pairs, E);
    build_csr<<<NBUCK, 256, 0, stream>>>(pairs, bcnt, deg, rowptr, dis, col, N);

    // prep: x cast (pre-scaled by dis) + all 4 weight transposes, one launch
    prep_kernel<<<CAST_BLOCKS + 896, 256, 0, stream>>>(
        x, dis, xh, W0, W1, W2, W3,
        (unsigned short*)wt0, (unsigned short*)wt1,
        (unsigned short*)wt2, (unsigned short*)wt3);

    // layer 0: agg0 = dis*(sum x'_src + x'_n) = A_hat x, then tanh(agg0 W0 + b0)
    msgpass_bf16<128, 128, false><<<(N + 3) / 4, 256, 0, stream>>>(
        xh, bufB, rowptr, deg, col, dis, nullptr);
    gemm_mfma<128, true><<<dim3((N + 127) / 128, 2), 256, 0, stream>>>(
        (const short*)bufB, wt0, b0, dis, bufA, N);

    // layers 1..3: hW' = dis*(h W) (GEMM epilogue); h = tanh(dis*(sum hW'_src
    // + hW'_n) + b) == tanh(A_hat (h W) + b). Full-width msgpass (W=256).
    const short* wts[3] = {wt1, wt2, wt3};
    const float* bs_[3] = {b1, b2, b3};
    for (int l = 0; l < 3; ++l) {
        gemm_mfma<256, false><<<dim3((N + 127) / 128, 2), 256, 0, stream>>>(
            (const short*)bufA, wts[l], nullptr, dis, bufB, N);
        msgpass_bf16<256, 256, true><<<(N + 3) / 4, 256, 0, stream>>>(
            bufB, bufA, rowptr, deg, col, dis, bs_[l]);
    }

    // pooling (atomic-free partials) + MLP (combines partials)
    pool_kernel<<<NGRAPH * PCHUNK, 256, 0, stream>>>(bufA, batch, psum, pmax, gcnt, N);
    mlp_kernel<<<NGRAPH, 1024, 0, stream>>>(psum, pmax, gcnt, fc1_w, fc1_b, fc2_w, fc2_b,
                                            out_w, out_b, out);
}

// Round 8
// 609.118 us; speedup vs baseline: 1.0522x; 1.0522x over previous
//
#include <hip/hip_runtime.h>
#include <hip/hip_bf16.h>

// ---------------------------------------------------------------------------
// GCN surface: 4x GCNConv(tanh) + global max/mean pool + 3-layer MLP
// Round 20 resubmit (container infra failure last round; no signal).
//   - revert round-19 regressions: msgpass back to feature-split W=128 pair
//     (2x52.2 < 110 full-width), GEMM epilogue back to scalar stores.
//   - single change vs round-18 (609.6us): gemm __launch_bounds__ 2 -> 3
//     blocks/CU (LDS 110.6KB fits; VGPR cap ~170 no-spill). Theory: 4-iter
//     K-loop at 2 waves/SIMD is staging-latency-bound; +50% TLP overlaps
//     stage with MFMA. Prediction: GEMMs -5-10us each -> total 580-595;
//     flat -> GEMMs at small-N roofline, pivot to dispatch fusion.
//   - keep: atomic-free CSR build + pooling, parallel MLP, ushort col,
//     BK=64 GEMM, prep fusion, 8-deep msgpass inner loop.
// ---------------------------------------------------------------------------

#define NNODES 50000
#define DDIM 256
#define NBUCK 196            // ceil(50000/256) buckets of 256 nodes
#define BCAP 16384           // slots per bucket region (mean 8163, max ~8500)
#define CHUNK_AB 6400        // edges per build_partition block
#define NGRAPH 64
#define PCHUNK 8             // pool chunks per graph

typedef __attribute__((ext_vector_type(8))) short short8;
typedef __attribute__((ext_vector_type(4))) float float4_;
typedef __attribute__((ext_vector_type(2))) float float2_;

__device__ __forceinline__ float fast_tanh(float x) {
    float e = __expf(2.0f * x);
    return 1.0f - 2.0f / (e + 1.0f);
}

__device__ __forceinline__ float bf2f(unsigned short u) {
    return __uint_as_float(((unsigned)u) << 16);
}
__device__ __forceinline__ unsigned short f2bf(float f) {
    unsigned u = __float_as_uint(f);
    u = u + 0x7fffu + ((u >> 16) & 1u);   // round-to-nearest-even
    return (unsigned short)(u >> 16);
}

// ---------------- CSR build: bucketed counting sort (no fabric atomics) -----
__global__ void build_partition(const int* __restrict__ ei, int* __restrict__ bcnt,
                                unsigned* __restrict__ pairs, int E) {
    __shared__ int hist[NBUCK];
    __shared__ int base[NBUCK];
    __shared__ int cursor[NBUCK];
    int t = threadIdx.x;
    int e0 = blockIdx.x * CHUNK_AB;
    int lim = E - e0;
    if (lim > CHUNK_AB) lim = CHUNK_AB;
    if (t < NBUCK) { hist[t] = 0; cursor[t] = 0; }
    __syncthreads();
    for (int i = t; i < lim; i += 256)
        atomicAdd(&hist[ei[E + e0 + i] >> 8], 1);
    __syncthreads();
    if (t < NBUCK) {
        int h = hist[t];
        base[t] = h ? atomicAdd(&bcnt[t], h) : 0;
    }
    __syncthreads();
    for (int i = t; i < lim; i += 256) {
        int dst = ei[E + e0 + i];
        int src = ei[e0 + i];
        int b = dst >> 8;
        int r = atomicAdd(&cursor[b], 1);
        pairs[(size_t)b * BCAP + base[b] + r] =
            ((unsigned)(dst & 255) << 16) | (unsigned)src;
    }
}

__global__ void build_csr(const unsigned* __restrict__ pairs, const int* __restrict__ bcnt,
                          int* __restrict__ deg, int* __restrict__ rowptr,
                          float* __restrict__ dis, unsigned short* __restrict__ col, int N) {
    __shared__ int sc[256];
    __shared__ int hist[256];
    __shared__ int cursor[256];
    int b = blockIdx.x;
    int t = threadIdx.x;
    sc[t] = (t < NBUCK) ? bcnt[t] : 0;
    __syncthreads();
    for (int off = 1; off < 256; off <<= 1) {
        int v = (t >= off) ? sc[t - off] : 0;
        __syncthreads();
        sc[t] += v;
        __syncthreads();
    }
    int bstart = (b == 0) ? 0 : sc[b - 1];
    int cnt = bcnt[b];
    __syncthreads();          // everyone has bstart before sc is reused
    hist[t] = 0; cursor[t] = 0;
    __syncthreads();
    const unsigned* bp = pairs + (size_t)b * BCAP;
    for (int i = t; i < cnt; i += 256)
        atomicAdd(&hist[bp[i] >> 16], 1);
    __syncthreads();
    sc[t] = hist[t];
    __syncthreads();
    for (int off = 1; off < 256; off <<= 1) {
        int v = (t >= off) ? sc[t - off] : 0;
        __syncthreads();
        sc[t] += v;
        __syncthreads();
    }
    int n = b * 256 + t;
    if (n < N) {
        int d = hist[t];
        deg[n] = d;
        dis[n] = rsqrtf(1.0f + (float)d);
        rowptr[n] = bstart + sc[t] - d;   // exclusive
    }
    __syncthreads();
    for (int i = t; i < cnt; i += 256) {
        unsigned p = bp[i];
        int low = p >> 16;
        int r = atomicAdd(&cursor[low], 1);
        col[bstart + (sc[low] - hist[low]) + r] = (unsigned short)(p & 0xffffu);
    }
}

// ---------------- prep: cast x (pre-scaled by dis) + 4 weight transposes ----
#define CAST_BLOCKS ((NNODES * 128) / 256)     // 25000
__global__ void prep_kernel(const float* __restrict__ x, const float* __restrict__ dis,
                            unsigned short* __restrict__ xh,
                            const float* __restrict__ W0, const float* __restrict__ W1,
                            const float* __restrict__ W2, const float* __restrict__ W3,
                            unsigned short* __restrict__ wt0, unsigned short* __restrict__ wt1,
                            unsigned short* __restrict__ wt2, unsigned short* __restrict__ wt3) {
    int b = blockIdx.x;
    int t = threadIdx.x;
    if (b < CAST_BLOCKS) {
        int i = b * 256 + t;
        xh[i] = f2bf(x[i] * dis[i >> 7]);   // 128 feats per row
        return;
    }
    b -= CAST_BLOCKS;
    const float* W; unsigned short* Wt; int K; int k;
    if (b < 128)      { W = W0; Wt = wt0; K = 128; k = b; }
    else if (b < 384) { W = W1; Wt = wt1; K = 256; k = b - 128; }
    else if (b < 640) { W = W2; Wt = wt2; K = 256; k = b - 384; }
    else              { W = W3; Wt = wt3; K = 256; k = b - 640; }
    Wt[t * K + k] = f2bf(W[k * 256 + t]);
}

// ---------------- message passing (feature-sliced) ----------------
__device__ __forceinline__ void paddu(float2_* acc, uint4 u) {
    float2_ v0 = {__uint_as_float(u.x << 16), __uint_as_float(u.x & 0xffff0000u)};
    float2_ v1 = {__uint_as_float(u.y << 16), __uint_as_float(u.y & 0xffff0000u)};
    float2_ v2 = {__uint_as_float(u.z << 16), __uint_as_float(u.z & 0xffff0000u)};
    float2_ v3 = {__uint_as_float(u.w << 16), __uint_as_float(u.w & 0xffff0000u)};
    acc[0] += v0; acc[1] += v1; acc[2] += v2; acc[3] += v3;
}
__device__ __forceinline__ void paddw(float2_* acc, uint4 u, float w) {
    float2_ w2 = {w, w};
    float2_ v0 = {__uint_as_float(u.x << 16), __uint_as_float(u.x & 0xffff0000u)};
    float2_ v1 = {__uint_as_float(u.y << 16), __uint_as_float(u.y & 0xffff0000u)};
    float2_ v2 = {__uint_as_float(u.z << 16), __uint_as_float(u.z & 0xffff0000u)};
    float2_ v3 = {__uint_as_float(u.w << 16), __uint_as_float(u.w & 0xffff0000u)};
    acc[0] += v0 * w2; acc[1] += v1 * w2; acc[2] += v2 * w2; acc[3] += v3 * w2;
}

template <int W, int S, bool FINALIZE>
__global__ void msgpass_bf16(const unsigned short* __restrict__ in,
                             unsigned short* __restrict__ out,
                             const int* __restrict__ rowptr, const int* __restrict__ deg,
                             const unsigned short* __restrict__ col,
                             const float* __restrict__ dis, const float* __restrict__ bias) {
    constexpr int L = W / 8;      // lanes per edge (16 for W=128)
    constexpr int P = 64 / L;     // edges per wave-issue (4 for W=128)
    int lane = threadIdx.x & 63;
    int wav  = threadIdx.x >> 6;
    int n = blockIdx.x * 4 + wav;   // block = 256 threads = 4 waves
    if (n >= NNODES) return;
    int part = lane / L;
    int sl   = lane % L;
    int start = rowptr[n];
    int cnt   = deg[n];
    float dn = dis[n];
    const uint4* inb = (const uint4*)in + sl;   // lane-fixed base
    float2_ acc[4];
#pragma unroll
    for (int j = 0; j < 4; ++j) { float2_ z = {0.0f, 0.0f}; acc[j] = z; }

    int e = 0;
    // 8-deep: 8 cols then 8 row-loads in flight, then unpack (static indices)
    for (; e + 8 * P <= cnt; e += 8 * P) {
        int c[8];
        uint4 u[8];
#pragma unroll
        for (int q = 0; q < 8; ++q)
            c[q] = col[start + e + q * P + part];
#pragma unroll
        for (int q = 0; q < 8; ++q)
            u[q] = *(inb + (size_t)c[q] * (S / 8));
#pragma unroll
        for (int q = 0; q < 8; ++q)
            paddu(acc, u[q]);
    }
    for (; e + 4 * P <= cnt; e += 4 * P) {
        int c0 = col[start + e + part];
        int c1 = col[start + e + P + part];
        int c2 = col[start + e + 2 * P + part];
        int c3 = col[start + e + 3 * P + part];
        uint4 u0 = *(inb + (size_t)c0 * (S / 8));
        uint4 u1 = *(inb + (size_t)c1 * (S / 8));
        uint4 u2 = *(inb + (size_t)c2 * (S / 8));
        uint4 u3 = *(inb + (size_t)c3 * (S / 8));
        paddu(acc, u0);
        paddu(acc, u1);
        paddu(acc, u2);
        paddu(acc, u3);
    }
    for (; e + P <= cnt; e += P) {
        int c = col[start + e + part];
        uint4 u = *(inb + (size_t)c * (S / 8));
        paddu(acc, u);
    }
    int r = cnt - e;
    if (r > 0) {
        int c = (part < r) ? (int)col[start + e + part] : n;
        float w = (part < r) ? 1.0f : 0.0f;
        uint4 u = *(inb + (size_t)c * (S / 8));
        paddw(acc, u, w);
    }
    {   // self term: + in[n] (part 0 only)
        float w = (part == 0) ? 1.0f : 0.0f;
        uint4 u = *(inb + (size_t)n * (S / 8));
        paddw(acc, u, w);
    }
    // reduce across parts (butterfly)
#pragma unroll
    for (int j = 0; j < 4; ++j) {
#pragma unroll
        for (int h = 0; h < 2; ++h) {
            if (P == 4) acc[j][h] += __shfl(acc[j][h], lane ^ 16);
            acc[j][h] += __shfl(acc[j][h], lane ^ 32);
        }
    }
    if (part == 0) {
        float a[8] = {acc[0][0], acc[0][1], acc[1][0], acc[1][1],
                      acc[2][0], acc[2][1], acc[3][0], acc[3][1]};
        if (FINALIZE) {
#pragma unroll
            for (int j = 0; j < 8; ++j)
                a[j] = fast_tanh(fmaf(a[j], dn, bias[sl * 8 + j]));
        } else {
#pragma unroll
            for (int j = 0; j < 8; ++j)
                a[j] *= dn;
        }
        uint4 o;
        o.x = (unsigned)f2bf(a[0]) | ((unsigned)f2bf(a[1]) << 16);
        o.y = (unsigned)f2bf(a[2]) | ((unsigned)f2bf(a[3]) << 16);
        o.z = (unsigned)f2bf(a[4]) | ((unsigned)f2bf(a[5]) << 16);
        o.w = (unsigned)f2bf(a[6]) | ((unsigned)f2bf(a[7]) << 16);
        *((uint4*)(out + (size_t)n * S) + sl) = o;
    }
}

// ---------------- MFMA GEMM: C[N,256] = A[N,K] * W[K,256], BK=64 ----------
template <int K, bool TANH>
__launch_bounds__(256, 3)
__global__ void gemm_mfma(const short* __restrict__ A, const short* __restrict__ Bt,
                          const float* __restrict__ bias, const float* __restrict__ dis,
                          unsigned short* __restrict__ C, int N) {
    constexpr int PK = 72;   // 64 + 8 pad (16B-aligned segments)
    __shared__ __align__(16) short As[128 * PK];
    __shared__ __align__(16) short Bs[128 * PK];
    int t = threadIdx.x;
    int lane = t & 63;
    int w    = t >> 6;
    int wr = w & 1;
    int wc = w >> 1;
    int m0 = blockIdx.x * 128;
    int n0 = blockIdx.y * 128;

    int srow = t >> 2;           // 0..63
    int koff = (t & 3) * 8;      // 0,8,16,24
    int arow0 = m0 + srow;      if (arow0 > N - 1) arow0 = N - 1;
    int arow1 = m0 + 64 + srow; if (arow1 > N - 1) arow1 = N - 1;
    const short8* ap0 = (const short8*)(A + (size_t)arow0 * K + koff);
    const short8* ap1 = (const short8*)(A + (size_t)arow1 * K + koff);
    const short8* bp0 = (const short8*)(Bt + (size_t)(n0 + srow) * K + koff);
    const short8* bp1 = (const short8*)(Bt + (size_t)(n0 + 64 + srow) * K + koff);

    float4_ acc[4][4];
#pragma unroll
    for (int i = 0; i < 4; ++i)
#pragma unroll
        for (int j = 0; j < 4; ++j) {
            float4_ z = {0.0f, 0.0f, 0.0f, 0.0f};
            acc[i][j] = z;
        }

    constexpr int NKB = K / 64;       // 4 for K=256, 2 for K=128
    int g = lane >> 4;
    int r = lane & 15;

    short8 a00 = ap0[0], a01 = ap0[4];
    short8 a10 = ap1[0], a11 = ap1[4];
    short8 b00 = bp0[0], b01 = bp0[4];
    short8 b10 = bp1[0], b11 = bp1[4];

    for (int kb = 0; kb < NKB; ++kb) {
        __syncthreads();
        *(short8*)&As[srow * PK + koff]             = a00;
        *(short8*)&As[srow * PK + koff + 32]        = a01;
        *(short8*)&As[(64 + srow) * PK + koff]      = a10;
        *(short8*)&As[(64 + srow) * PK + koff + 32] = a11;
        *(short8*)&Bs[srow * PK + koff]             = b00;
        *(short8*)&Bs[srow * PK + koff + 32]        = b01;
        *(short8*)&Bs[(64 + srow) * PK + koff]      = b10;
        *(short8*)&Bs[(64 + srow) * PK + koff + 32] = b11;
        __syncthreads();
        if (kb + 1 < NKB) {
            int o = (kb + 1) * 8;
            a00 = ap0[o]; a01 = ap0[o + 4];
            a10 = ap1[o]; a11 = ap1[o + 4];
            b00 = bp0[o]; b01 = bp0[o + 4];
            b10 = bp1[o]; b11 = bp1[o + 4];
        }
#pragma unroll
        for (int s = 0; s < 2; ++s) {
            short8 af[4], bfr[4];
#pragma unroll
            for (int i = 0; i < 4; ++i)
                af[i] = *(const short8*)&As[(wr * 64 + i * 16 + r) * PK + s * 32 + g * 8];
#pragma unroll
            for (int j = 0; j < 4; ++j)
                bfr[j] = *(const short8*)&Bs[(wc * 64 + j * 16 + r) * PK + s * 32 + g * 8];
#pragma unroll
            for (int i = 0; i < 4; ++i)
#pragma unroll
                for (int j = 0; j < 4; ++j)
                    acc[i][j] = __builtin_amdgcn_mfma_f32_16x16x32_bf16(af[i], bfr[j],
                                                                        acc[i][j], 0, 0, 0);
        }
    }

#pragma unroll
    for (int i = 0; i < 4; ++i) {
        int rowb = m0 + wr * 64 + i * 16 + g * 4;
#pragma unroll
        for (int rr = 0; rr < 4; ++rr) {
            int row = rowb + rr;
            if (row < N) {
                float dsc = TANH ? 0.0f : dis[row];
#pragma unroll
                for (int j = 0; j < 4; ++j) {
                    int cb = n0 + wc * 64 + j * 16 + r;
                    float v = acc[i][j][rr];
                    if (TANH) v = fast_tanh(v + bias[cb]);
                    else      v = v * dsc;
                    C[(size_t)row * 256 + cb] = f2bf(v);
                }
            }
        }
    }
}

// ---------------- pooling: sorted batch, per-graph chunks, NO atomics -------
__global__ void pool_kernel(const unsigned short* __restrict__ act,
                            const int* __restrict__ batch,
                            float* __restrict__ psum, float* __restrict__ pmax,
                            int* __restrict__ gcnt, int N) {
    int g = blockIdx.x >> 3;        // graph
    int c = blockIdx.x & 7;         // chunk
    int t = threadIdx.x;            // 256 = DDIM
    __shared__ int bounds[2];
    if (t < 2) {
        int target = g + t;         // t=0: first idx with batch>=g; t=1: >=g+1
        int lo = 0, hi = N;
        while (lo < hi) {
            int m = (lo + hi) >> 1;
            if (batch[m] < target) lo = m + 1; else hi = m;
        }
        bounds[t] = lo;
    }
    __syncthreads();
    int s = bounds[0];
    int e = bounds[1];
    int len = e - s;
    if (len < 0) len = 0;
    if (c == 0 && t == 0) gcnt[g] = len;
    int n0 = s + (int)(((long long)len * c) >> 3);
    int n1 = s + (int)(((long long)len * (c + 1)) >> 3);
    float sum = 0.0f, mx = -2.0f;
    int n = n0;
    for (; n + 4 <= n1; n += 4) {
        float v0 = bf2f(act[(size_t)(n + 0) * DDIM + t]);
        float v1 = bf2f(act[(size_t)(n + 1) * DDIM + t]);
        float v2 = bf2f(act[(size_t)(n + 2) * DDIM + t]);
        float v3 = bf2f(act[(size_t)(n + 3) * DDIM + t]);
        sum += (v0 + v1) + (v2 + v3);
        mx = fmaxf(fmaxf(mx, v0), fmaxf(fmaxf(v1, v2), v3));
    }
    for (; n < n1; ++n) {
        float v = bf2f(act[(size_t)n * DDIM + t]);
        sum += v;
        mx = fmaxf(mx, v);
    }
    psum[(size_t)blockIdx.x * DDIM + t] = sum;
    pmax[(size_t)blockIdx.x * DDIM + t] = mx;
}

// ---------------- fused MLP, 1024 thr/block, k-split + LDS combine ----------
__launch_bounds__(1024, 1)
__global__ void mlp_kernel(const float* __restrict__ psum, const float* __restrict__ pmax,
                           const int* __restrict__ gcnt,
                           const float* __restrict__ fc1_w, const float* __restrict__ fc1_b,
                           const float* __restrict__ fc2_w, const float* __restrict__ fc2_b,
                           const float* __restrict__ out_w, const float* __restrict__ out_b,
                           float* __restrict__ out) {
    int g = blockIdx.x;
    int t = threadIdx.x;   // 1024
    __shared__ float gv[512];
    __shared__ float t1[512];
    __shared__ float t2[256];
    __shared__ float ps[2][512];
    __shared__ float ps2[4][256];
    __shared__ float pso[32][16];
    if (t < 512) {
        if (t < 256) {
            float m = pmax[(size_t)(g * PCHUNK) * DDIM + t];
#pragma unroll
            for (int c = 1; c < PCHUNK; ++c)
                m = fmaxf(m, pmax[(size_t)(g * PCHUNK + c) * DDIM + t]);
            gv[t] = m;
        } else {
            int tt = t - 256;
            float sm = 0.0f;
#pragma unroll
            for (int c = 0; c < PCHUNK; ++c)
                sm += psum[(size_t)(g * PCHUNK + c) * DDIM + tt];
            float cnt = fmaxf((float)gcnt[g], 1.0f);
            gv[t] = sm / cnt;
        }
    }
    __syncthreads();
    {   // fc1: j in [0,512), h in {0,1}, 256-long partial each
        int j = t & 511;
        int h = t >> 9;
        float a = 0.0f;
        const float* wp = fc1_w + (size_t)(h * 256) * 512 + j;
#pragma unroll 8
        for (int k = 0; k < 256; ++k)
            a = fmaf(gv[h * 256 + k], wp[(size_t)k * 512], a);
        ps[h][j] = a;
    }
    __syncthreads();
    if (t < 512)
        t1[t] = fmaxf(ps[0][t] + ps[1][t] + fc1_b[t], 0.0f);
    __syncthreads();
    {   // fc2: j in [0,256), h in {0..3}, 128-long partial each
        int j = t & 255;
        int h = t >> 8;
        float a = 0.0f;
        const float* wp = fc2_w + (size_t)(h * 128) * 256 + j;
#pragma unroll 8
        for (int k = 0; k < 128; ++k)
            a = fmaf(t1[h * 128 + k], wp[(size_t)k * 256], a);
        ps2[h][j] = a;
    }
    __syncthreads();
    if (t < 256)
        t2[t] = fmaxf(ps2[0][t] + ps2[1][t] + ps2[2][t] + ps2[3][t] + fc2_b[t], 0.0f);
    __syncthreads();
    if (t < 512) {   // out: j in [0,16) (j<10 live), h in [0,32), 8-long partial
        int j = t & 15;
        int h = t >> 4;
        float a = 0.0f;
        if (j < 10) {
#pragma unroll
            for (int k = 0; k < 8; ++k)
                a = fmaf(t2[h * 8 + k], out_w[(size_t)(h * 8 + k) * 10 + j], a);
        }
        pso[h][j] = a;
    }
    __syncthreads();
    if (t < 10) {
        float o = out_b[t];
#pragma unroll
        for (int h = 0; h < 32; ++h)
            o += pso[h][t];
        out[g * 10 + t] = o;
    }
}

// ---------------------------------------------------------------------------
extern "C" void kernel_launch(void* const* d_in, const int* in_sizes, int n_in,
                              void* d_out, int out_size, void* d_ws, size_t ws_size,
                              hipStream_t stream) {
    const float* x      = (const float*)d_in[0];
    const int*   ei     = (const int*)d_in[1];
    const int*   batch  = (const int*)d_in[2];
    const float* W0     = (const float*)d_in[3];
    const float* b0     = (const float*)d_in[4];
    const float* W1     = (const float*)d_in[5];
    const float* b1     = (const float*)d_in[6];
    const float* W2     = (const float*)d_in[7];
    const float* b2     = (const float*)d_in[8];
    const float* W3     = (const float*)d_in[9];
    const float* b3     = (const float*)d_in[10];
    const float* fc1_w  = (const float*)d_in[11];
    const float* fc1_b  = (const float*)d_in[12];
    const float* fc2_w  = (const float*)d_in[13];
    const float* fc2_b  = (const float*)d_in[14];
    const float* out_w  = (const float*)d_in[15];
    const float* out_b  = (const float*)d_in[16];
    float* out = (float*)d_out;

    const int N = in_sizes[2];          // 50000
    const int E = in_sizes[1] / 2;      // 1600000

    // workspace layout (bytes)
    char* ws = (char*)d_ws;
    const size_t off_deg    = 0;          // 200000 (written by build_csr)
    const size_t off_gcnt   = 331264;     // 256 (written by pool, no zero)
    const size_t off_dis    = 331776;     // 200000
    const size_t off_rowptr = 531968;     // 200000
    const size_t off_bcnt   = 732160;     // 1024   (zeroed)
    const size_t off_col    = 932352;     // E*2 = 3200000 (ushort)
    const size_t off_xh     = 7332352;    // 12800000
    const size_t off_wt0    = 20132352;   // 65536
    const size_t off_wt1    = 20197888;   // 131072
    const size_t off_wt2    = 20328960;   // 131072
    const size_t off_wt3    = 20460032;   // 131072
    const size_t off_bufA   = 20591104;   // 25600000
    const size_t off_bufB   = 46191104;   // 25600000

    int*            deg    = (int*)(ws + off_deg);
    int*            gcnt   = (int*)(ws + off_gcnt);
    float*          dis    = (float*)(ws + off_dis);
    int*            rowptr = (int*)(ws + off_rowptr);
    int*            bcnt   = (int*)(ws + off_bcnt);
    unsigned short* col    = (unsigned short*)(ws + off_col);
    unsigned short* xh     = (unsigned short*)(ws + off_xh);
    short*          wt0    = (short*)(ws + off_wt0);
    short*          wt1    = (short*)(ws + off_wt1);
    short*          wt2    = (short*)(ws + off_wt2);
    short*          wt3    = (short*)(ws + off_wt3);
    unsigned short* bufA   = (unsigned short*)(ws + off_bufA);
    unsigned short* bufB   = (unsigned short*)(ws + off_bufB);
    // pairs overlay: 196*16384*4 = 12.84 MB, dead before first GEMM writes bufA
    unsigned*       pairs  = (unsigned*)(ws + off_bufA);
    // pool partials overlay on xh (dead after layer-0 msgpass)
    float*          psum   = (float*)(ws + off_xh);
    float*          pmax   = (float*)(ws + off_xh + 524288);

    hipMemsetAsync(ws + off_bcnt, 0, 1024, stream);

    // CSR build (atomic-free hot path)
    build_partition<<<(E + CHUNK_AB - 1) / CHUNK_AB, 256, 0, stream>>>(ei, bcnt, pairs, E);
    build_csr<<<NBUCK, 256, 0, stream>>>(pairs, bcnt, deg, rowptr, dis, col, N);

    // prep: x cast (pre-scaled by dis) + all 4 weight transposes, one launch
    prep_kernel<<<CAST_BLOCKS + 896, 256, 0, stream>>>(
        x, dis, xh, W0, W1, W2, W3,
        (unsigned short*)wt0, (unsigned short*)wt1,
        (unsigned short*)wt2, (unsigned short*)wt3);

    // layer 0: agg0 = dis*(sum x'_src + x'_n) = A_hat x, then tanh(agg0 W0 + b0)
    msgpass_bf16<128, 128, false><<<(N + 3) / 4, 256, 0, stream>>>(
        xh, bufB, rowptr, deg, col, dis, nullptr);
    gemm_mfma<128, true><<<dim3((N + 127) / 128, 2), 256, 0, stream>>>(
        (const short*)bufB, wt0, b0, dis, bufA, N);

    // layers 1..3: hW' = dis*(h W) (GEMM epilogue); h = tanh(dis*(sum hW'_src
    // + hW'_n) + b) == tanh(A_hat (h W) + b). Feature-split msgpass pair.
    const short* wts[3] = {wt1, wt2, wt3};
    const float* bs_[3] = {b1, b2, b3};
    for (int l = 0; l < 3; ++l) {
        gemm_mfma<256, false><<<dim3((N + 127) / 128, 2), 256, 0, stream>>>(
            (const short*)bufA, wts[l], nullptr, dis, bufB, N);
        msgpass_bf16<128, 256, true><<<(N + 3) / 4, 256, 0, stream>>>(
            bufB, bufA, rowptr, deg, col, dis, bs_[l]);
        msgpass_bf16<128, 256, true><<<(N + 3) / 4, 256, 0, stream>>>(
            bufB + 128, bufA + 128, rowptr, deg, col, dis, bs_[l] + 128);
    }

    // pooling (atomic-free partials) + MLP (combines partials)
    pool_kernel<<<NGRAPH * PCHUNK, 256, 0, stream>>>(bufA, batch, psum, pmax, gcnt, N);
    mlp_kernel<<<NGRAPH, 1024, 0, stream>>>(psum, pmax, gcnt, fc1_w, fc1_b, fc2_w, fc2_b,
                                            out_w, out_b, out);
}